// Round 3
// baseline (447.069 us; speedup 1.0000x reference)
//
#include <hip/hip_runtime.h>
#include <math.h>

#define BATCH 4096
#define DIN   2048
#define DOUT  2048
#define DEPTH 16

typedef unsigned short u16;
typedef __attribute__((ext_vector_type(8))) short short8;    // 8 bf16 = 4 VGPRs
typedef __attribute__((ext_vector_type(16))) float f32x16;   // 32x32 MFMA acc

// ---------- helpers ----------

__device__ static inline unsigned bf16_rn(float x) {
    unsigned u = __float_as_uint(x);
    return (u + 0x7FFFu + ((u >> 16) & 1u)) >> 16;  // RN-even to bf16 bits
}

__device__ static inline float tanh_fast(float z) {
    float zc = fminf(fmaxf(z, -15.0f), 15.0f);
    float e = __builtin_amdgcn_exp2f(zc * 2.8853900817779268f);  // exp(2z)
    return (e - 1.0f) * __builtin_amdgcn_rcpf(e + 1.0f);
}

__device__ static inline void async16(u16* lds, const u16* g) {
    __builtin_amdgcn_global_load_lds(
        (const __attribute__((address_space(1))) void*)g,
        (__attribute__((address_space(3))) void*)lds, 16, 0, 0);
}

// ---------- probs: probs[j] = (prod cos(W[d,j,g]))^2 / DIN ----------
__global__ __launch_bounds__(256) void probs_kernel(const float* __restrict__ W,
                                                    float* __restrict__ probs) {
    int tid = threadIdx.x;
    int jl = tid >> 4, d = tid & 15;
    int j = blockIdx.x * 16 + jl;
    const float* p = W + (size_t)d * DIN * DOUT + (size_t)j * DOUT;
    float pr = cosf(p[0]) * cosf(p[1]) * cosf(p[2]);
#pragma unroll
    for (int off = 1; off < 16; off <<= 1) pr *= __shfl_xor(pr, off, 16);
    if (d == 0) probs[j] = pr * pr * (1.0f / (float)DIN);
}

// ---------- x -> hi/lo bf16 (RN split) ----------
__global__ __launch_bounds__(256) void convert_x_kernel(const float* __restrict__ x,
                                                        u16* __restrict__ xh,
                                                        u16* __restrict__ xl) {
    int i = (blockIdx.x * 256 + threadIdx.x) * 4;
    float4 v = *(const float4*)(x + i);
    float vv[4] = {v.x, v.y, v.z, v.w};
    u16 hh[4], ll[4];
#pragma unroll
    for (int c = 0; c < 4; ++c) {
        unsigned hb = bf16_rn(vv[c]);
        hh[c] = (u16)hb;
        float r = vv[c] - __uint_as_float(hb << 16);
        ll[c] = (u16)bf16_rn(r);
    }
    ushort4 h, l;
    h.x = hh[0]; h.y = hh[1]; h.z = hh[2]; h.w = hh[3];
    l.x = ll[0]; l.y = ll[1]; l.z = ll[2]; l.w = ll[3];
    *(ushort4*)(xh + i) = h;
    *(ushort4*)(xl + i) = l;
}

// ---------- W[k][n] -> Wt_hi/Wt_lo[n][k] (transpose + RN split) ----------
__global__ __launch_bounds__(256) void transpose_w_kernel(const float* __restrict__ W,
                                                          u16* __restrict__ wh,
                                                          u16* __restrict__ wl) {
    __shared__ float t[32][33];
    int n0 = blockIdx.x * 32, k0 = blockIdx.y * 32;
    int tx = threadIdx.x & 31, ty = threadIdx.x >> 5;  // ty 0..7
#pragma unroll
    for (int i = 0; i < 4; ++i)
        t[ty + i * 8][tx] = W[(size_t)(k0 + ty + i * 8) * DOUT + n0 + tx];
    __syncthreads();
#pragma unroll
    for (int i = 0; i < 4; ++i) {
        float v = t[tx][ty + i * 8];
        size_t o = (size_t)(n0 + ty + i * 8) * DIN + k0 + tx;
        unsigned hb = bf16_rn(v);
        wh[o] = (u16)hb;
        float r = v - __uint_as_float(hb << 16);
        wl[o] = (u16)bf16_rn(r);
    }
}

// ---------- MFMA GEMM: C = tanh(x@W + bias + probs), bf16x3, 32x32x16 ----------
// 128x128 block, 4 waves (2x2), each wave 2x2 tiles of 32x32, BK=32 (2 k-chunks).
// LDS rows of 32 bf16 (64B); 16B-chunk XOR swizzle: q_phys = q ^ ((row>>1)&3).
__global__ __launch_bounds__(256, 2) void gemm_mfma_kernel(
    const u16* __restrict__ xh, const u16* __restrict__ xl,
    const u16* __restrict__ wh, const u16* __restrict__ wl,
    const float* __restrict__ bias, const float* __restrict__ probs,
    float* __restrict__ C)
{
    __shared__ u16 sAh[4096];
    __shared__ u16 sAl[4096];
    __shared__ u16 sBh[4096];
    __shared__ u16 sBl[4096];

    const int tid = threadIdx.x;
    const int lane = tid & 63;
    const int wave = tid >> 6;
    const int bR = blockIdx.y * 128;
    const int bC = blockIdx.x * 128;

    // Each wave DMAs one array (A_hi/A_lo/B_hi/B_lo), 8 chunks of 1KB.
    const u16* gsrc = (wave == 0) ? xh + (size_t)bR * DIN
                    : (wave == 1) ? xl + (size_t)bR * DIN
                    : (wave == 2) ? wh + (size_t)bC * DIN
                                  : wl + (size_t)bC * DIN;
    u16* lbase = (wave == 0) ? sAh : (wave == 1) ? sAl : (wave == 2) ? sBh : sBl;

    int goff[8];
#pragma unroll
    for (int i = 0; i < 8; ++i) {
        int row = i * 16 + (lane >> 2);
        int lq = (lane & 3) ^ ((row >> 1) & 3);  // logical chunk landing at phys lane&3
        goff[i] = row * DIN + lq * 8;
    }

    const int wm = wave >> 1, wn = wave & 1;
    const int colL = lane & 31;      // 32x32 operand: m/n index
    const int half = lane >> 5;      // k-half within chunk

    // frag LDS offsets: A[m][k], m = tile_row + colL, k = c*16 + half*8 + j
    int aoff[2][2], boff[2][2];
#pragma unroll
    for (int mt = 0; mt < 2; ++mt)
#pragma unroll
        for (int c = 0; c < 2; ++c) {
            int r = wm * 64 + mt * 32 + colL;
            int q = (c * 2 + half) ^ ((r >> 1) & 3);
            aoff[mt][c] = r * 32 + q * 8;
        }
#pragma unroll
    for (int nt = 0; nt < 2; ++nt)
#pragma unroll
        for (int c = 0; c < 2; ++c) {
            int r = wn * 64 + nt * 32 + colL;
            int q = (c * 2 + half) ^ ((r >> 1) & 3);
            boff[nt][c] = r * 32 + q * 8;
        }

    f32x16 acc[2][2];
#pragma unroll
    for (int mt = 0; mt < 2; ++mt)
#pragma unroll
        for (int nt = 0; nt < 2; ++nt)
#pragma unroll
            for (int r = 0; r < 16; ++r) acc[mt][nt][r] = 0.f;

    for (int k0 = 0; k0 < DIN; k0 += 32) {
        __syncthreads();  // prior iteration's frag reads done before overwrite
#pragma unroll
        for (int i = 0; i < 8; ++i)
            async16(lbase + i * 512, gsrc + goff[i] + k0);
        __syncthreads();  // drains vmcnt before barrier (m97 structure)

        short8 ah[2][2], al[2][2], bh[2][2], bl[2][2];
#pragma unroll
        for (int mt = 0; mt < 2; ++mt)
#pragma unroll
            for (int c = 0; c < 2; ++c) {
                ah[mt][c] = *(const short8*)&sAh[aoff[mt][c]];
                al[mt][c] = *(const short8*)&sAl[aoff[mt][c]];
            }
#pragma unroll
        for (int nt = 0; nt < 2; ++nt)
#pragma unroll
            for (int c = 0; c < 2; ++c) {
                bh[nt][c] = *(const short8*)&sBh[boff[nt][c]];
                bl[nt][c] = *(const short8*)&sBl[boff[nt][c]];
            }

#pragma unroll
        for (int mt = 0; mt < 2; ++mt)
#pragma unroll
            for (int nt = 0; nt < 2; ++nt)
#pragma unroll
                for (int c = 0; c < 2; ++c) {
                    acc[mt][nt] = __builtin_amdgcn_mfma_f32_32x32x16_bf16(
                        ah[mt][c], bh[nt][c], acc[mt][nt], 0, 0, 0);
                    acc[mt][nt] = __builtin_amdgcn_mfma_f32_32x32x16_bf16(
                        ah[mt][c], bl[nt][c], acc[mt][nt], 0, 0, 0);
                    acc[mt][nt] = __builtin_amdgcn_mfma_f32_32x32x16_bf16(
                        al[mt][c], bh[nt][c], acc[mt][nt], 0, 0, 0);
                }
    }

    // epilogue: 32x32 C/D map col=lane&31, row=(reg&3)+8*(reg>>2)+4*(lane>>5)
    // (verified m74/m101)
#pragma unroll
    for (int nt = 0; nt < 2; ++nt) {
        int ccol = bC + wn * 64 + nt * 32 + colL;
        float bp = bias[ccol] + probs[ccol];
#pragma unroll
        for (int mt = 0; mt < 2; ++mt) {
#pragma unroll
            for (int reg = 0; reg < 16; ++reg) {
                int rrow = bR + wm * 64 + mt * 32 + 4 * half + (reg & 3) + 8 * (reg >> 2);
                C[(size_t)rrow * DOUT + ccol] = tanh_fast(acc[mt][nt][reg] + bp);
            }
        }
    }
}

extern "C" void kernel_launch(void* const* d_in, const int* in_sizes, int n_in,
                              void* d_out, int out_size, void* d_ws, size_t ws_size,
                              hipStream_t stream) {
    const float* x  = (const float*)d_in[0];  // [4096, 2048]
    const float* W  = (const float*)d_in[1];  // [16, 2048, 2048]
    const float* cw = (const float*)d_in[2];  // [2048, 2048]
    const float* cb = (const float*)d_in[3];  // [2048]
    float* out = (float*)d_out;

    // ws layout: probs f32[2048] | x_hi | x_lo | wt_hi | wt_lo  (bf16 bits as u16)
    const size_t PROBS_B = 8192;
    const size_t XSZ = (size_t)BATCH * DIN;   // 8388608
    const size_t WSZ = (size_t)DIN * DOUT;    // 4194304

    float* probs = (float*)d_ws;
    u16* xh = (u16*)((char*)d_ws + PROBS_B);
    u16* xl = xh + XSZ;
    u16* wh = xl + XSZ;
    u16* wl = wh + WSZ;

    probs_kernel<<<DOUT / 16, 256, 0, stream>>>(W, probs);
    convert_x_kernel<<<XSZ / 4 / 256, 256, 0, stream>>>(x, xh, xl);
    transpose_w_kernel<<<dim3(DOUT / 32, DIN / 32), 256, 0, stream>>>(cw, wh, wl);

    dim3 grid(DOUT / 128, BATCH / 128);
    gemm_mfma_kernel<<<grid, 256, 0, stream>>>(xh, xl, wh, wl, cb, probs, out);
}